// Round 2
// baseline (136.680 us; speedup 1.0000x reference)
//
#include <hip/hip_runtime.h>

typedef float v2f __attribute__((ext_vector_type(2)));

// Problem constants
#define HW      1024   // H*W = BN channel count (spatial positions)
#define NLAYERS 30
#define TPB     64     // ONE wave per channel: 64 elems/thread, no barriers

// ---------------------------------------------------------------------------
// DPP-based wave64 sum (proven in round 0): pure VALU, lane63 = total.
// ---------------------------------------------------------------------------
template <int CTRL, int RMASK>
__device__ __forceinline__ float dpp_add(float x) {
    int t = __builtin_amdgcn_update_dpp(0, __builtin_bit_cast(int, x),
                                        CTRL, RMASK, 0xf, true);
    return x + __builtin_bit_cast(float, t);
}
__device__ __forceinline__ float wave_sum64(float x) {
    x = dpp_add<0x111, 0xf>(x);   // row_shr:1
    x = dpp_add<0x112, 0xf>(x);   // row_shr:2
    x = dpp_add<0x114, 0xf>(x);   // row_shr:4
    x = dpp_add<0x118, 0xf>(x);   // row_shr:8
    x = dpp_add<0x142, 0xa>(x);   // row_bcast15 -> rows 1,3
    x = dpp_add<0x143, 0xc>(x);   // row_bcast31 -> rows 2,3
    return x;                     // lane 63 = wave total
}

// ---------------------------------------------------------------------------
// Fused 30-layer ODE, ONE WAVE per BN channel p (XCD-swizzled block id).
// Lane owns c = lane + 64j (j=0..3), all b=0..15 -> 64 elems = 32 v2f.
// Per layer: z = fma(m,x1,y) + s/q accumulate, DPP reduce + shfl broadcast
// (no LDS, no barrier), BN constants, apply with med3 clamp, y += dt*(a-y).
// Next layer's m/dt prefetched before the body; L2-resident loads.
// ---------------------------------------------------------------------------
__global__ __launch_bounds__(TPB, 1) void ode_wave(
    const float* __restrict__ x, const float* __restrict__ delta_t,
    const float* __restrict__ matrices, const float* __restrict__ gamma,
    const float* __restrict__ beta, float* __restrict__ out) {

    const int bid  = blockIdx.x;
    const int p    = ((bid & 7) << 7) | (bid >> 3);   // XCD-contiguous channel
    const int lane = threadIdx.x;                     // 0..63

    // Gather column p: element (b, c) at x[(b*256 + c)*1024 + p].
    v2f x1[4][8], y[4][8], z[4][8];
#pragma unroll
    for (int j = 0; j < 4; ++j) {
        const size_t base = (size_t)(lane + 64 * j) * HW + p;
#pragma unroll
        for (int i = 0; i < 8; ++i) {
            x1[j][i].x = x[base + (size_t)(2 * i)     * 256 * HW];
            x1[j][i].y = x[base + (size_t)(2 * i + 1) * 256 * HW];
            y[j][i] = x1[j][i];
        }
    }

    const float gp = gamma[p];
    const float bp = beta[p];

    // Prefetch layer 0's per-c scalars (coalesced 256B per j-group) + dt.
    float mn[4];
#pragma unroll
    for (int j = 0; j < 4; ++j) mn[j] = matrices[64 * j + lane];
    float dtn = delta_t[0];

    for (int lay = 0; lay < NLAYERS; ++lay) {
        const float dt = __builtin_amdgcn_fmed3f(dtn, 0.0f, 6.0f);
        v2f M[4];
#pragma unroll
        for (int j = 0; j < 4; ++j) { M[j].x = mn[j]; M[j].y = mn[j]; }

        // Prefetch next layer's m/dt; latency hides under this layer's body.
        const int nl = (lay < NLAYERS - 1) ? lay + 1 : lay;
#pragma unroll
        for (int j = 0; j < 4; ++j) mn[j] = matrices[nl * 256 + 64 * j + lane];
        dtn = delta_t[nl];

        // z = y + m*x1 ; accumulate sum and sum-of-squares (8 indep chains).
        v2f s[4], q[4];
#pragma unroll
        for (int j = 0; j < 4; ++j) {
            s[j] = (v2f){0.0f, 0.0f};
            q[j] = (v2f){0.0f, 0.0f};
        }
#pragma unroll
        for (int j = 0; j < 4; ++j) {
#pragma unroll
            for (int i = 0; i < 8; ++i) {
                const v2f zz = __builtin_elementwise_fma(M[j], x1[j][i], y[j][i]);
                z[j][i] = zz;
                s[j] += zz;
                q[j] = __builtin_elementwise_fma(zz, zz, q[j]);
            }
        }

        const v2f sv = (s[0] + s[1]) + (s[2] + s[3]);
        const v2f qv = (q[0] + q[1]) + (q[2] + q[3]);
        const float ssum = wave_sum64(sv.x + sv.y);   // two independent chains
        const float qsum = wave_sum64(qv.x + qv.y);
        const float S = __shfl(ssum, 63, 64);         // broadcast lane 63
        const float Q = __shfl(qsum, 63, 64);

        const float mean = S * (1.0f / 4096.0f);
        const float var  = fmaf(-mean, mean, Q * (1.0f / 4096.0f));
        const float rstd = rsqrtf(var + 1e-5f);
        const float g    = gp * rstd;            // fold gamma into scale
        const float bb   = fmaf(-mean, g, bp);   // fold mean into bias
        const v2f g2 = {g, g}, b2 = {bb, bb}, dt2 = {dt, dt};

        // a = med3(g*z+bb, 0, 6); y += dt*(a - y)   [== (1-dt)y + dt*a]
#pragma unroll
        for (int j = 0; j < 4; ++j) {
#pragma unroll
            for (int i = 0; i < 8; ++i) {
                v2f a = __builtin_elementwise_fma(z[j][i], g2, b2);
                a.x = __builtin_amdgcn_fmed3f(a.x, 0.0f, 6.0f);
                a.y = __builtin_amdgcn_fmed3f(a.y, 0.0f, 6.0f);
                const v2f d = a - y[j][i];
                y[j][i] = __builtin_elementwise_fma(dt2, d, y[j][i]);
            }
        }
    }

    // Scatter out = y + x1 (same addressing as gather).
#pragma unroll
    for (int j = 0; j < 4; ++j) {
        const size_t base = (size_t)(lane + 64 * j) * HW + p;
#pragma unroll
        for (int i = 0; i < 8; ++i) {
            out[base + (size_t)(2 * i)     * 256 * HW] = y[j][i].x + x1[j][i].x;
            out[base + (size_t)(2 * i + 1) * 256 * HW] = y[j][i].y + x1[j][i].y;
        }
    }
}

extern "C" void kernel_launch(void* const* d_in, const int* in_sizes, int n_in,
                              void* d_out, int out_size, void* d_ws, size_t ws_size,
                              hipStream_t stream) {
    const float* x        = (const float*)d_in[0];   // [16,256,32,32]
    const float* delta_t  = (const float*)d_in[1];   // [30,1]
    const float* matrices = (const float*)d_in[2];   // [30,1,1,16,16]
    const float* gamma    = (const float*)d_in[3];   // [1024]
    const float* beta     = (const float*)d_in[4];   // [1024]
    float* out = (float*)d_out;

    ode_wave<<<dim3(HW), dim3(TPB), 0, stream>>>(x, delta_t, matrices, gamma, beta, out);
}

// Round 3
// 123.041 us; speedup vs baseline: 1.1109x; 1.1109x over previous
//
#include <hip/hip_runtime.h>

typedef float v2f __attribute__((ext_vector_type(2)));
typedef float v4f __attribute__((ext_vector_type(4)));

// Problem constants
#define HW      1024   // H*W = BN channel count (spatial positions)
#define NLAYERS 30
#define TPB     512    // 2 channels/block, 8 waves, 16 elems/thread/channel-pair

// ---------------------------------------------------------------------------
// DPP-based wave64 sum (proven): pure VALU, lane 63 = wave total.
// ---------------------------------------------------------------------------
template <int CTRL, int RMASK>
__device__ __forceinline__ float dpp_add(float x) {
    int t = __builtin_amdgcn_update_dpp(0, __builtin_bit_cast(int, x),
                                        CTRL, RMASK, 0xf, true);
    return x + __builtin_bit_cast(float, t);
}
__device__ __forceinline__ float wave_sum64(float x) {
    x = dpp_add<0x111, 0xf>(x);   // row_shr:1
    x = dpp_add<0x112, 0xf>(x);   // row_shr:2
    x = dpp_add<0x114, 0xf>(x);   // row_shr:4
    x = dpp_add<0x118, 0xf>(x);   // row_shr:8
    x = dpp_add<0x142, 0xa>(x);   // row_bcast15 -> rows 1,3
    x = dpp_add<0x143, 0xc>(x);   // row_bcast31 -> rows 2,3
    return x;                     // lane 63 = wave total
}

// ---------------------------------------------------------------------------
// Fused 30-layer ODE, TWO BN channels {p0,p0+1} per 512-thread block.
// Thread t: c = t&255, batch rows b = 2i + (t>>8); each v2f spans the two
// channels -> dwordx2 gather/scatter, per-thread VALU identical to the
// 1-channel/256-thread version. BN sums separate into .x/.y components.
// Per layer ONE fused element pass: apply layer k (med3 clamp, Euler) and
// compute z/s/q of layer k+1. One barrier per layer; stats via lane63
// float4 -> LDS (2-slot parity) -> 8 broadcast reads + tree add.
// m/dt prefetched from L2 (no LDS staging; LDS = 256 B).
// ---------------------------------------------------------------------------
__global__ __launch_bounds__(TPB, 4) void ode2ch(
    const float* __restrict__ x, const float* __restrict__ delta_t,
    const float* __restrict__ matrices, const float* __restrict__ gamma,
    const float* __restrict__ beta, float* __restrict__ out) {

    const int bid = blockIdx.x;                      // 0..511
    const int gs  = ((bid & 7) << 6) | (bid >> 3);   // XCD-contiguous group
    const int p0  = gs << 1;                         // channel pair base
    const int t   = threadIdx.x;
    const int c   = t & 255;                         // matrix element index
    const int bb0 = t >> 8;                          // 0/1: batch row parity
    const int wid = t >> 6;                          // wave id 0..7
    const int lane = t & 63;

    __shared__ v4f red[2][8];                        // [parity][wave]=(sx,sy,qx,qy)

    // Gather: element (b,c) of channels p0,p0+1 as one v2f (8B of each line).
    v2f x1[8], y[8], z[8];
#pragma unroll
    for (int i = 0; i < 8; ++i) {
        const size_t off = (size_t)((2 * i + bb0) * 256 + c) * HW + p0;
        x1[i] = *(const v2f*)(x + off);
        y[i]  = x1[i];
    }

    const v2f gp2 = *(const v2f*)(gamma + p0);
    const v2f bp2 = *(const v2f*)(beta + p0);

    // Layer 0: z0 = x1 + m0*x1 (y0 = x1), reduce, post partials.
    {
        const float m0 = matrices[c];
        const v2f M0 = {m0, m0};
        v2f s = {0.f, 0.f}, q = {0.f, 0.f};
#pragma unroll
        for (int i = 0; i < 8; ++i) {
            z[i] = __builtin_elementwise_fma(M0, x1[i], y[i]);
            s += z[i];
            q = __builtin_elementwise_fma(z[i], z[i], q);
        }
        const float sx = wave_sum64(s.x), sy = wave_sum64(s.y);
        const float qx = wave_sum64(q.x), qy = wave_sum64(q.y);
        if (lane == 63) { v4f w; w.x = sx; w.y = sy; w.z = qx; w.w = qy; red[0][wid] = w; }
    }

    float m_cur  = matrices[256 + c];    // m_1 (for z_1 in body k=0)
    float dt_cur = delta_t[0];
    float dt_nxt = delta_t[1];
    __syncthreads();

    for (int k = 0; k < NLAYERS - 1; ++k) {
        // Prefetch m_{k+2}, dt_{k+2}; land under stats + apply.
        const int k2 = (k + 2 < NLAYERS) ? k + 2 : NLAYERS - 1;
        const float m_nxt  = matrices[k2 * 256 + c];
        const float dt_nn  = delta_t[k2];

        // Stats of layer k from red[k&1]: 8 broadcast reads + tree add.
        const v4f* r = red[k & 1];
        v4f a0 = r[0] + r[1], a1 = r[2] + r[3], a2 = r[4] + r[5], a3 = r[6] + r[7];
        const v4f acc = (a0 + a1) + (a2 + a3);

        const float dtk = __builtin_amdgcn_fmed3f(dt_cur, 0.0f, 6.0f);
        const v2f mean2 = {acc.x * (1.0f / 4096.0f), acc.y * (1.0f / 4096.0f)};
        const v2f msq2  = {acc.z * (1.0f / 4096.0f), acc.w * (1.0f / 4096.0f)};
        const v2f var2  = __builtin_elementwise_fma(-mean2, mean2, msq2);
        v2f rstd; rstd.x = rsqrtf(var2.x + 1e-5f); rstd.y = rsqrtf(var2.y + 1e-5f);
        const v2f g2 = gp2 * rstd;                                   // gamma folded
        const v2f b2 = __builtin_elementwise_fma(-mean2, g2, bp2);   // mean folded
        const v2f dt2 = {dtk, dtk};
        const v2f M2  = {m_cur, m_cur};

        // Fused pass: apply layer k, then z/s/q of layer k+1.
        v2f s = {0.f, 0.f}, q = {0.f, 0.f};
#pragma unroll
        for (int i = 0; i < 8; ++i) {
            v2f a = __builtin_elementwise_fma(z[i], g2, b2);
            a.x = __builtin_amdgcn_fmed3f(a.x, 0.0f, 6.0f);
            a.y = __builtin_amdgcn_fmed3f(a.y, 0.0f, 6.0f);
            const v2f d = a - y[i];
            y[i] = __builtin_elementwise_fma(dt2, d, y[i]);          // Euler step
            z[i] = __builtin_elementwise_fma(M2, x1[i], y[i]);       // next layer z
            s += z[i];
            q = __builtin_elementwise_fma(z[i], z[i], q);
        }
        const float sx = wave_sum64(s.x), sy = wave_sum64(s.y);
        const float qx = wave_sum64(q.x), qy = wave_sum64(q.y);
        if (lane == 63) { v4f w; w.x = sx; w.y = sy; w.z = qx; w.w = qy; red[(k + 1) & 1][wid] = w; }

        m_cur = m_nxt; dt_cur = dt_nxt; dt_nxt = dt_nn;
        __syncthreads();
    }

    // Final layer (k = 29): stats from red[1], apply, scatter out = y + x1.
    {
        const v4f* r = red[(NLAYERS - 1) & 1];
        v4f a0 = r[0] + r[1], a1 = r[2] + r[3], a2 = r[4] + r[5], a3 = r[6] + r[7];
        const v4f acc = (a0 + a1) + (a2 + a3);

        const float dtk = __builtin_amdgcn_fmed3f(dt_cur, 0.0f, 6.0f);
        const v2f mean2 = {acc.x * (1.0f / 4096.0f), acc.y * (1.0f / 4096.0f)};
        const v2f msq2  = {acc.z * (1.0f / 4096.0f), acc.w * (1.0f / 4096.0f)};
        const v2f var2  = __builtin_elementwise_fma(-mean2, mean2, msq2);
        v2f rstd; rstd.x = rsqrtf(var2.x + 1e-5f); rstd.y = rsqrtf(var2.y + 1e-5f);
        const v2f g2 = gp2 * rstd;
        const v2f b2 = __builtin_elementwise_fma(-mean2, g2, bp2);
        const v2f dt2 = {dtk, dtk};

#pragma unroll
        for (int i = 0; i < 8; ++i) {
            v2f a = __builtin_elementwise_fma(z[i], g2, b2);
            a.x = __builtin_amdgcn_fmed3f(a.x, 0.0f, 6.0f);
            a.y = __builtin_amdgcn_fmed3f(a.y, 0.0f, 6.0f);
            const v2f d = a - y[i];
            const v2f yf = __builtin_elementwise_fma(dt2, d, y[i]);
            const size_t off = (size_t)((2 * i + bb0) * 256 + c) * HW + p0;
            *(v2f*)(out + off) = yf + x1[i];
        }
    }
}

extern "C" void kernel_launch(void* const* d_in, const int* in_sizes, int n_in,
                              void* d_out, int out_size, void* d_ws, size_t ws_size,
                              hipStream_t stream) {
    const float* x        = (const float*)d_in[0];   // [16,256,32,32]
    const float* delta_t  = (const float*)d_in[1];   // [30,1]
    const float* matrices = (const float*)d_in[2];   // [30,1,1,16,16]
    const float* gamma    = (const float*)d_in[3];   // [1024]
    const float* beta     = (const float*)d_in[4];   // [1024]
    float* out = (float*)d_out;

    ode2ch<<<dim3(HW / 2), dim3(TPB), 0, stream>>>(x, delta_t, matrices, gamma, beta, out);
}

// Round 4
// 117.742 us; speedup vs baseline: 1.1608x; 1.0450x over previous
//
#include <hip/hip_runtime.h>

typedef float v2f __attribute__((ext_vector_type(2)));
typedef float v4f __attribute__((ext_vector_type(4)));

// Problem constants
#define HW      1024   // H*W = BN channel count (spatial positions)
#define NLAYERS 30
#define TPB     256    // 4 waves; block owns TWO channels, 16 elems/thread each

// ---------------------------------------------------------------------------
// Packed-f32 VOP3P ops (gfx90a+/gfx950). The compiler scalarizes v2f math to
// 2x v_fma_f32; these halve the element-pass instruction count.
// ---------------------------------------------------------------------------
static __device__ __forceinline__ v2f pk_fma(v2f a, v2f b, v2f c) {
    v2f d; asm("v_pk_fma_f32 %0, %1, %2, %3" : "=v"(d) : "v"(a), "v"(b), "v"(c));
    return d;
}
static __device__ __forceinline__ v2f pk_add(v2f a, v2f b) {
    v2f d; asm("v_pk_add_f32 %0, %1, %2" : "=v"(d) : "v"(a), "v"(b));
    return d;
}
static __device__ __forceinline__ v2f pk_mul(v2f a, v2f b) {
    v2f d; asm("v_pk_mul_f32 %0, %1, %2" : "=v"(d) : "v"(a), "v"(b));
    return d;
}

// ---------------------------------------------------------------------------
// DPP-based wave64 sum (proven): pure VALU, lane 63 = wave total.
// ---------------------------------------------------------------------------
template <int CTRL, int RMASK>
__device__ __forceinline__ float dpp_add(float x) {
    int t = __builtin_amdgcn_update_dpp(0, __builtin_bit_cast(int, x),
                                        CTRL, RMASK, 0xf, true);
    return x + __builtin_bit_cast(float, t);
}
__device__ __forceinline__ float wave_sum64(float x) {
    x = dpp_add<0x111, 0xf>(x);   // row_shr:1
    x = dpp_add<0x112, 0xf>(x);   // row_shr:2
    x = dpp_add<0x114, 0xf>(x);   // row_shr:4
    x = dpp_add<0x118, 0xf>(x);   // row_shr:8
    x = dpp_add<0x142, 0xa>(x);   // row_bcast15 -> rows 1,3
    x = dpp_add<0x143, 0xc>(x);   // row_bcast31 -> rows 2,3
    return x;                     // lane 63 = wave total
}

struct Stats { v2f g2, b2; };

// BN constants from 4-wave partials: 2x ds_read_b128 + 6 adds + rsqrt.
__device__ __forceinline__ Stats bn_stats(const v4f* r, float gp, float bp) {
    const v4f r0 = r[0], r1 = r[1];          // (s0,q0,s1,q1),(s2,q2,s3,q3)
    const float S = (r0.x + r0.z) + (r1.x + r1.z);
    const float Q = (r0.y + r0.w) + (r1.y + r1.w);
    const float mean = S * (1.0f / 4096.0f);
    const float var  = fmaf(-mean, mean, Q * (1.0f / 4096.0f));
    const float rstd = rsqrtf(var + 1e-5f);
    const float g    = gp * rstd;            // fold gamma into scale
    const float b    = fmaf(-mean, g, bp);   // fold mean into bias
    Stats st; st.g2 = (v2f){g, g}; st.b2 = (v2f){b, b};
    return st;
}

// One channel's fused layer pass: apply layer k (clamp+Euler), build layer
// k+1's z and its sum / sum-of-squares partials. 8 packed + 16 med3 insts.
__device__ __forceinline__ void pass_channel(const v2f (&x1)[8], v2f (&y)[8], v2f (&z)[8],
                                             v2f g2, v2f b2, v2f dt2, v2f om2, v2f M2,
                                             float& s_out, float& q_out) {
    v2f s = {0.f, 0.f}, q = {0.f, 0.f};
#pragma unroll
    for (int i = 0; i < 8; ++i) {
        v2f a = pk_fma(z[i], g2, b2);
        a.x = __builtin_amdgcn_fmed3f(a.x, 0.0f, 6.0f);
        a.y = __builtin_amdgcn_fmed3f(a.y, 0.0f, 6.0f);
        y[i] = pk_mul(om2, y[i]);            // y *= (1-dt)
        y[i] = pk_fma(dt2, a, y[i]);         // y += dt*a
        z[i] = pk_fma(M2, x1[i], y[i]);      // next layer z
        s = pk_add(s, z[i]);
        q = pk_fma(z[i], z[i], q);
    }
    s_out = wave_sum64(s.x + s.y);
    q_out = wave_sum64(q.x + q.y);
}

// ---------------------------------------------------------------------------
// Fused 30-layer ODE. Block owns channels {p0, p0+1} in SEPARATE register
// state, software-pipelined: statsA/dppA chains hide under passB and vice
// versa. 4-wave barrier domain (cheap combine tree), 1 barrier/layer for
// both channels. Gather/scatter dwordx2 spanning the channel pair.
// ---------------------------------------------------------------------------
__global__ __launch_bounds__(TPB, 2) void ode_pipe(
    const float* __restrict__ x, const float* __restrict__ delta_t,
    const float* __restrict__ matrices, const float* __restrict__ gamma,
    const float* __restrict__ beta, float* __restrict__ out) {

    const int bid = blockIdx.x;                      // 0..511
    const int gs  = ((bid & 7) << 6) | (bid >> 3);   // XCD-contiguous pair id
    const int p0  = gs << 1;                         // channels p0, p0+1
    const int t   = threadIdx.x;                     // c = t (matrix elem idx)
    const int wid = t >> 6;
    const int lane = t & 63;

    __shared__ __align__(16) v2f red[2][2][4];       // [parity][ch][wave]=(s,q)

    // Gather: elems e = t + 256k; dwordx2 spans the channel pair, then a
    // 2x2 register transpose separates per-channel v2f (batch-paired).
    v2f xA[8], xB[8], yA[8], yB[8], zA[8], zB[8];
#pragma unroll
    for (int k = 0; k < 8; ++k) {
        const size_t e0 = (size_t)(t + 512 * k);
        const size_t e1 = e0 + 256;
        const v2f u = *(const v2f*)(x + e0 * HW + p0);
        const v2f v = *(const v2f*)(x + e1 * HW + p0);
        xA[k] = (v2f){u.x, v.x};
        xB[k] = (v2f){u.y, v.y};
        yA[k] = xA[k];
        yB[k] = xB[k];
    }

    const v2f gp = *(const v2f*)(gamma + p0);
    const v2f bp = *(const v2f*)(beta + p0);

    // Layer 0: z0 = x1 + m0*x1 (y0 = x1); reduce; post partials to red[0].
    {
        const float m0 = matrices[t];
        const v2f M0 = {m0, m0};
        v2f sA = {0.f, 0.f}, qA = {0.f, 0.f}, sB = {0.f, 0.f}, qB = {0.f, 0.f};
#pragma unroll
        for (int i = 0; i < 8; ++i) {
            zA[i] = pk_fma(M0, xA[i], yA[i]);
            sA = pk_add(sA, zA[i]);
            qA = pk_fma(zA[i], zA[i], qA);
            zB[i] = pk_fma(M0, xB[i], yB[i]);
            sB = pk_add(sB, zB[i]);
            qB = pk_fma(zB[i], zB[i], qB);
        }
        const float sa = wave_sum64(sA.x + sA.y), qa = wave_sum64(qA.x + qA.y);
        const float sb = wave_sum64(sB.x + sB.y), qb = wave_sum64(qB.x + qB.y);
        if (lane == 63) {
            red[0][0][wid] = (v2f){sa, qa};
            red[0][1][wid] = (v2f){sb, qb};
        }
    }

    float m_cur  = matrices[256 + t];   // m_1 (builds z_1 in iter k=0)
    float dt_cur = delta_t[0];
    float dt_nxt = delta_t[1];
    __syncthreads();

#pragma unroll 2
    for (int k = 0; k < NLAYERS - 1; ++k) {
        // Prefetch m_{k+2}/dt_{k+2}; lands under this layer's body.
        const int k2 = (k + 2 < NLAYERS) ? k + 2 : NLAYERS - 1;
        const float m_nxt = matrices[k2 * 256 + t];
        const float dt_nn = delta_t[k2];

        const int par = k & 1;
        const Stats stA = bn_stats((const v4f*)&red[par][0][0], gp.x, bp.x);
        const Stats stB = bn_stats((const v4f*)&red[par][1][0], gp.y, bp.y);

        const float dtk = __builtin_amdgcn_fmed3f(dt_cur, 0.0f, 6.0f);
        const v2f dt2 = {dtk, dtk};
        const v2f om2 = {1.0f - dtk, 1.0f - dtk};
        const v2f M2  = {m_cur, m_cur};

        float sa, qa, sb, qb;
        pass_channel(xA, yA, zA, stA.g2, stA.b2, dt2, om2, M2, sa, qa);
        if (lane == 63) red[par ^ 1][0][wid] = (v2f){sa, qa};
        pass_channel(xB, yB, zB, stB.g2, stB.b2, dt2, om2, M2, sb, qb);
        if (lane == 63) red[par ^ 1][1][wid] = (v2f){sb, qb};

        m_cur = m_nxt; dt_cur = dt_nxt; dt_nxt = dt_nn;
        __syncthreads();
    }

    // Final layer (k = 29): stats from red[1], apply, scatter out = y + x1.
    {
        const Stats stA = bn_stats((const v4f*)&red[1][0][0], gp.x, bp.x);
        const Stats stB = bn_stats((const v4f*)&red[1][1][0], gp.y, bp.y);
        const float dtk = __builtin_amdgcn_fmed3f(dt_cur, 0.0f, 6.0f);
        const v2f dt2 = {dtk, dtk};
        const v2f om2 = {1.0f - dtk, 1.0f - dtk};

#pragma unroll
        for (int i = 0; i < 8; ++i) {
            v2f aA = pk_fma(zA[i], stA.g2, stA.b2);
            aA.x = __builtin_amdgcn_fmed3f(aA.x, 0.0f, 6.0f);
            aA.y = __builtin_amdgcn_fmed3f(aA.y, 0.0f, 6.0f);
            yA[i] = pk_mul(om2, yA[i]);
            yA[i] = pk_fma(dt2, aA, yA[i]);
            v2f aB = pk_fma(zB[i], stB.g2, stB.b2);
            aB.x = __builtin_amdgcn_fmed3f(aB.x, 0.0f, 6.0f);
            aB.y = __builtin_amdgcn_fmed3f(aB.y, 0.0f, 6.0f);
            yB[i] = pk_mul(om2, yB[i]);
            yB[i] = pk_fma(dt2, aB, yB[i]);
        }

#pragma unroll
        for (int k = 0; k < 8; ++k) {
            const size_t e0 = (size_t)(t + 512 * k);
            const size_t e1 = e0 + 256;
            const v2f u = {yA[k].x + xA[k].x, yB[k].x + xB[k].x};
            const v2f v = {yA[k].y + xA[k].y, yB[k].y + xB[k].y};
            *(v2f*)(out + e0 * HW + p0) = u;
            *(v2f*)(out + e1 * HW + p0) = v;
        }
    }
}

extern "C" void kernel_launch(void* const* d_in, const int* in_sizes, int n_in,
                              void* d_out, int out_size, void* d_ws, size_t ws_size,
                              hipStream_t stream) {
    const float* x        = (const float*)d_in[0];   // [16,256,32,32]
    const float* delta_t  = (const float*)d_in[1];   // [30,1]
    const float* matrices = (const float*)d_in[2];   // [30,1,1,16,16]
    const float* gamma    = (const float*)d_in[3];   // [1024]
    const float* beta     = (const float*)d_in[4];   // [1024]
    float* out = (float*)d_out;

    ode_pipe<<<dim3(HW / 2), dim3(TPB), 0, stream>>>(x, delta_t, matrices, gamma, beta, out);
}